// Round 2
// 95.268 us; speedup vs baseline: 1.0075x; 1.0075x over previous
//
#include <hip/hip_runtime.h>
#include <hip/hip_bf16.h>
#include <math.h>

// NT-Xent loss, N=4096, D=256 -> 2N=8192 rows.
// R13 = R12 resubmit (round-1 failure was "container failed twice" infra,
// no kernel signal; bounds/layout re-audited, in-bounds).
// R12: simsum was LATENCY bound (R10: MfmaUtil 13%; R11 reg-repack was
// neutral -> compiler won't keep 2 load groups in flight at 64 VGPR).
// Fix: canonical LDS staging. Each 128x128 tile block stages A/B panels
// (2 x 32KB of zT16) via global_load_lds width=16 ONCE, then the K-loop is
// pure ds_read_b128 + MFMA. LDS group layout [kk][ig][q][row][16B] matches
// the linear lane*16 DMA dest, and every ds_read group is a wave-contiguous
// 1KB read -> 0 bank conflicts by construction. 64KB LDS -> 2 blocks/CU so
// next block's staging overlaps this block's MFMAs.
// K1 prep: normalize -> fp8 -> zT16[c2][row] (c2 = quad*4 + kk, 16B entry).
// K3 coalesced reduce -> rowsum.  K4 loss.  K5 final.

static constexpr int ROWS  = 8192;
static constexpr int NPAIR = 4096;
static constexpr int DIM   = 256;            // bytes per fp8 row
static constexpr int NTILE = 64 * 65 / 2;    // 2080
static constexpr float EXP_SCALE = 14.426950408889634f;  // 10/ln2

typedef float f32x4 __attribute__((ext_vector_type(4)));
typedef long  l2v  __attribute__((ext_vector_type(2)));

template <int CTRL>
__device__ __forceinline__ float dpp_add(float x) {
    int t = __builtin_amdgcn_update_dpp(
        0, __builtin_bit_cast(int, x), CTRL, 0xF, 0xF, true);
    return x + __builtin_bit_cast(float, t);
}
__device__ __forceinline__ float sum16(float x) {
    x = dpp_add<0xB1>(x);   // xor 1
    x = dpp_add<0x4E>(x);   // xor 2
    x = dpp_add<0x141>(x);  // xor 4 (row_half_mirror)
    x = dpp_add<0x140>(x);  // xor 8 (row_mirror)
    return x;
}
__device__ __forceinline__ float sum64(float x) {
    x = sum16(x);
    x += __shfl_xor(x, 16);
    x += __shfl_xor(x, 32);
    return x;
}

// ---------------- K1: normalize -> fp8 -> packed zT16 ----------------
// zT16[(c2*8192 + row)*16] : c2 = quad*4 + kk, entry = 16 bytes =
//   z[row][64kk+8q .. +7] ++ z[row][64kk+32+8q .. +7]
__global__ void __launch_bounds__(256) prep_kernel(
        const float* __restrict__ z1, const float* __restrict__ z2,
        unsigned char* __restrict__ zT16, float* __restrict__ invnorm) {
    __shared__ int Ls[16 * 64];   // 16 rows x 256B
    const int tid  = threadIdx.x;
    const int wave = tid >> 6;
    const int lane = tid & 63;
    const int r0   = blockIdx.x * 16;

    #pragma unroll
    for (int it = 0; it < 4; ++it) {
        const int row = r0 + it * 4 + wave;
        const float* src = (row < NPAIR) ? (z1 + (size_t)row * DIM)
                                         : (z2 + (size_t)(row - NPAIR) * DIM);
        float4 v = ((const float4*)src)[lane];
        float ss = sum64(v.x * v.x + v.y * v.y + v.z * v.z + v.w * v.w);
        float invn = 1.0f / fmaxf(sqrtf(ss), 1e-12f);
        int p = __builtin_amdgcn_cvt_pk_fp8_f32(v.x * invn, v.y * invn, 0, false);
        p     = __builtin_amdgcn_cvt_pk_fp8_f32(v.z * invn, v.w * invn, p, true);
        Ls[(it * 4 + wave) * 64 + lane] = p;
        if (lane == 0) invnorm[row] = invn;
    }
    __syncthreads();
    // thread t -> c2 = t>>4, row r = t&15
    const int c2 = tid >> 4;
    const int r  = tid & 15;
    const int quad = c2 >> 2;
    const int kk   = c2 & 3;
    const int d0 = 16 * kk + 2 * quad;
    int4 o;
    o.x = Ls[r * 64 + d0];
    o.y = Ls[r * 64 + d0 + 1];
    o.z = Ls[r * 64 + d0 + 8];
    o.w = Ls[r * 64 + d0 + 9];
    *(int4*)(zT16 + ((size_t)c2 * ROWS + r0 + r) * 16) = o;
}

// ---------------- K2: symmetric fp8 Gram, LDS-staged ----------------
// LDS: A panel [0,32KB), B panel [32KB,64KB).
// Panel layout: 32 groups of 1KB, group g: kk = g>>3, ig = g&7.
// Within a group the DMA writes lane*16 -> internal order [q][row][16B]
// (lane = q*16 + row). Compute reads the whole 1KB contiguously -> 0 bank
// conflicts without any swizzle.
__global__ void __launch_bounds__(256, 2) simsum_kernel(
        const unsigned char* __restrict__ zT16, float* __restrict__ partial) {
    // decode linear tile index -> (by, bx), bx >= by
    const int t = blockIdx.x;
    int by = (int)floorf((129.0f - sqrtf(16641.0f - 8.0f * (float)t)) * 0.5f);
    by = max(0, min(by, 63));
    while (64 * (by + 1) - ((by + 1) * by) / 2 <= t) by++;
    while (64 * by - (by * (by - 1)) / 2 > t) by--;
    const int bx = by + (t - (64 * by - (by * (by - 1)) / 2));
    const int rowBase = by * 128;
    const int colBase = bx * 128;

    const int tid  = threadIdx.x;
    const int wave = tid >> 6;
    const int lane = tid & 63;
    const int lc   = lane & 15;
    const int quad = lane >> 4;
    const int waveRow = (wave >> 1) * 64;
    const int waveCol = (wave & 1) * 64;

    __shared__ __align__(16) unsigned char lds[65536];

    // ---- stage both panels: waves 0,1 -> A rows, waves 2,3 -> B cols ----
    {
        const int halfSel = wave >> 1;                   // 0=A, 1=B
        const int pbase   = halfSel ? colBase : rowBase; // panel row base
        #pragma unroll
        for (int it = 0; it < 16; ++it) {
            const int g  = ((wave & 1) << 4) | it;       // 0..31
            const int kk = g >> 3;
            const int ig = g & 7;
            const unsigned char* src = zT16
                + ((size_t)(4 * quad + kk) * ROWS + pbase + 16 * ig + lc) * 16;
            __builtin_amdgcn_global_load_lds(
                (const __attribute__((address_space(1))) unsigned int*)src,
                (__attribute__((address_space(3))) unsigned int*)
                    &lds[(halfSel << 15) + kk * 8192 + ig * 1024],
                16, 0, 0);
        }
    }
    __syncthreads();

    // ---- compute: pure ds_read_b128 + MFMA ----
    const int aig = (wave >> 1) * 4;   // A group-row base for this wave
    const int bgi = (wave & 1) * 4;    // B group-row base for this wave
    const unsigned char* lA = &lds[quad * 256 + lc * 16];
    const unsigned char* lB = &lds[32768 + quad * 256 + lc * 16];

    f32x4 acc[4][4];
    #pragma unroll
    for (int i = 0; i < 4; i++)
        #pragma unroll
        for (int j = 0; j < 4; j++)
            acc[i][j] = (f32x4)(0.0f);

    #pragma unroll
    for (int kk = 0; kk < 4; kk++) {
        l2v va[4], vb[4];
        #pragma unroll
        for (int i = 0; i < 4; i++)
            va[i] = *(const l2v*)(lA + kk * 8192 + (aig + i) * 1024);
        #pragma unroll
        for (int j = 0; j < 4; j++)
            vb[j] = *(const l2v*)(lB + kk * 8192 + (bgi + j) * 1024);
        // ks = 2kk (lo halves)
        #pragma unroll
        for (int i = 0; i < 4; i++)
            #pragma unroll
            for (int j = 0; j < 4; j++)
                acc[i][j] = __builtin_amdgcn_mfma_f32_16x16x32_fp8_fp8(
                    va[i].x, vb[j].x, acc[i][j], 0, 0, 0);
        // ks = 2kk+1 (hi halves)
        #pragma unroll
        for (int i = 0; i < 4; i++)
            #pragma unroll
            for (int j = 0; j < 4; j++)
                acc[i][j] = __builtin_amdgcn_mfma_f32_16x16x32_fp8_fp8(
                    va[i].y, vb[j].y, acc[i][j], 0, 0, 0);
    }

    // Epilogue. C/D 16x16: col=lane&15, row=quad*4+reg [m89].
    // Privatized unique-writer slots, SLOT-MAJOR: partial[slot*8192 + row].
    float* prow = partial + (size_t)(bx * 2 + (waveCol >> 6)) * ROWS;
    if (bx == by) {
        #pragma unroll
        for (int i = 0; i < 4; i++) {
            #pragma unroll
            for (int r = 0; r < 4; r++) {
                const int grow = rowBase + waveRow + 16 * i + quad * 4 + r;
                float s = 0.0f;
                #pragma unroll
                for (int j = 0; j < 4; j++) {
                    const int gcol = colBase + waveCol + 16 * j + lc;
                    float e = __builtin_amdgcn_exp2f(acc[i][j][r] * EXP_SCALE);
                    s += (grow == gcol) ? 0.0f : e;
                }
                s = sum16(s);
                if (lc == 0) prow[grow] = s;
            }
        }
    } else {
        float* pcol = partial + (size_t)(by * 2 + (waveRow >> 6)) * ROWS;
        float colacc[4] = {0.0f, 0.0f, 0.0f, 0.0f};
        #pragma unroll
        for (int i = 0; i < 4; i++) {
            #pragma unroll
            for (int r = 0; r < 4; r++) {
                const int grow = rowBase + waveRow + 16 * i + quad * 4 + r;
                float s = 0.0f;
                #pragma unroll
                for (int j = 0; j < 4; j++) {
                    float e = __builtin_amdgcn_exp2f(acc[i][j][r] * EXP_SCALE);
                    s += e;
                    colacc[j] += e;
                }
                s = sum16(s);
                if (lc == 0) prow[grow] = s;
            }
        }
        #pragma unroll
        for (int j = 0; j < 4; j++) {
            float c = colacc[j];
            c += __shfl_xor(c, 16);
            c += __shfl_xor(c, 32);
            if (lane < 16) pcol[colBase + waveCol + 16 * j + lc] = c;
        }
    }
}

// ---------------- K3: coalesced transpose-reduce partial -> rowsum ----------
__global__ void __launch_bounds__(256) reduce_kernel(
        const float* __restrict__ partial, float* __restrict__ rowsum) {
    const int tid  = threadIdx.x;
    const int wave = tid >> 6;
    const int lane = tid & 63;
    const int r0 = blockIdx.x * 64;
    float s = 0.0f;
    #pragma unroll
    for (int k = 0; k < 32; ++k) {
        const int slot = wave + k * 4;
        s += partial[(size_t)slot * ROWS + r0 + lane];
    }
    __shared__ float red[4][64];
    red[wave][lane] = s;
    __syncthreads();
    if (wave == 0)
        rowsum[r0 + lane] = red[0][lane] + red[1][lane]
                          + red[2][lane] + red[3][lane];
}

// ---------------- K4: per-pair loss -> blockpart (no atomics) ----------------
__global__ void __launch_bounds__(256) loss_kernel(
        const float* __restrict__ z1, const float* __restrict__ z2,
        const float* __restrict__ invnorm, const float* __restrict__ rowsum,
        float* __restrict__ blockpart) {
    const int tid  = threadIdx.x;
    const int wave = tid >> 6;
    const int lane = tid & 63;
    const int p = blockIdx.x * 4 + wave;     // pair 0..4095; rows p, p+NPAIR
    float4 a = ((const float4*)(z1 + (size_t)p * DIM))[lane];
    float4 b = ((const float4*)(z2 + (size_t)p * DIM))[lane];
    float d = sum64(a.x * b.x + a.y * b.y + a.z * b.z + a.w * b.w);
    __shared__ float wp[4];
    if (lane == 0) {
        float sim = d * invnorm[p] * invnorm[p + NPAIR] * 10.0f;
        wp[wave] = logf(rowsum[p]) + logf(rowsum[p + NPAIR]) - 2.0f * sim;
    }
    __syncthreads();
    if (tid == 0)
        blockpart[blockIdx.x] = wp[0] + wp[1] + wp[2] + wp[3];
}

// ---------------- K5: final reduce (single block) ----------------
__global__ void __launch_bounds__(256) final_kernel(
        const float* __restrict__ blockpart, float* __restrict__ out) {
    const int tid = threadIdx.x;
    float s = blockpart[tid] + blockpart[tid + 256]
            + blockpart[tid + 512] + blockpart[tid + 768];
    s = sum64(s);
    __shared__ float wpart[4];
    if ((tid & 63) == 0) wpart[tid >> 6] = s;
    __syncthreads();
    if (tid == 0)
        out[0] = (wpart[0] + wpart[1] + wpart[2] + wpart[3]) * (1.0f / ROWS);
}

extern "C" void kernel_launch(void* const* d_in, const int* in_sizes, int n_in,
                              void* d_out, int out_size, void* d_ws, size_t ws_size,
                              hipStream_t stream) {
    const float* z1 = (const float*)d_in[0];
    const float* z2 = (const float*)d_in[1];
    float* out = (float*)d_out;

    char* ws = (char*)d_ws;
    unsigned char* zT16 = (unsigned char*)ws;                       // 2 MiB
    float* partial   = (float*)(ws + (size_t)2 * 1024 * 1024);      // 4 MiB [slot][row]
    float* invnorm   = (float*)(ws + (size_t)6 * 1024 * 1024);      // 32 KiB
    float* rowsum    = (float*)(ws + (size_t)6 * 1024 * 1024 + 32768);   // 32 KiB
    float* blockpart = (float*)(ws + (size_t)6 * 1024 * 1024 + 65536);   // 4 KiB

    prep_kernel<<<ROWS / 16, 256, 0, stream>>>(z1, z2, zT16, invnorm);
    simsum_kernel<<<NTILE, 256, 0, stream>>>(zT16, partial);
    reduce_kernel<<<ROWS / 64, 256, 0, stream>>>(partial, rowsum);
    loss_kernel<<<NPAIR / 4, 256, 0, stream>>>(z1, z2, invnorm, rowsum, blockpart);
    final_kernel<<<1, 256, 0, stream>>>(blockpart, out);
}

// Round 3
// 90.819 us; speedup vs baseline: 1.0569x; 1.0490x over previous
//
#include <hip/hip_runtime.h>
#include <hip/hip_bf16.h>
#include <math.h>

// NT-Xent loss, N=4096, D=256 -> 2N=8192 rows.
// R14: A/B/A evidence (R12==R13 resubmit: +-0.7us noise; R11 reg-pipelined
// vs R13 LDS-staged simsum: 96.4 vs 95.3) => simsum is NOT the dominant
// term anymore; total is dominated by per-iteration invariants (268MB d_ws
// re-poison fill ~41us in the timed window + dispatch gaps). Remaining
// controllable cost: dispatch count + redundant HBM traffic.
// Restructure: 2N*loss = sum_rows log(rowsum) - 2*sum_pairs sim_p.
//   K1 prep: normalize -> fp8 -> zT16, AND compute pair sims in-register
//            (block handles z1 rows p0..p0+7 and z2 rows p0..p0+7, so pair
//            (p,p+4096) lives in one wave -> dot is a free sum64).
//   K2 simsum: unchanged R13 LDS-staged fp8 Gram (0 bank conflicts).
//   K3 logsum: partial -> sum log(rowsum) per 64 rows (no rowsum store).
//   K4 final: out = (sum logpart - 2*sum pairpart)/8192.
// 4 dispatches (was 5); old K4's 8MB z1/z2 re-read eliminated.

static constexpr int ROWS  = 8192;
static constexpr int NPAIR = 4096;
static constexpr int DIM   = 256;            // f32 elems per row / bytes per fp8 row
static constexpr int NTILE = 64 * 65 / 2;    // 2080
static constexpr float EXP_SCALE = 14.426950408889634f;  // 10/ln2

typedef float f32x4 __attribute__((ext_vector_type(4)));
typedef long  l2v  __attribute__((ext_vector_type(2)));

template <int CTRL>
__device__ __forceinline__ float dpp_add(float x) {
    int t = __builtin_amdgcn_update_dpp(
        0, __builtin_bit_cast(int, x), CTRL, 0xF, 0xF, true);
    return x + __builtin_bit_cast(float, t);
}
__device__ __forceinline__ float sum16(float x) {
    x = dpp_add<0xB1>(x);   // xor 1
    x = dpp_add<0x4E>(x);   // xor 2
    x = dpp_add<0x141>(x);  // xor 4 (row_half_mirror)
    x = dpp_add<0x140>(x);  // xor 8 (row_mirror)
    return x;
}
__device__ __forceinline__ float sum64(float x) {
    x = sum16(x);
    x += __shfl_xor(x, 16);
    x += __shfl_xor(x, 32);
    return x;
}

// ---------------- K1: normalize -> fp8 -> zT16, + pair sims ----------------
// Block b handles pairs p0..p0+7 (p0 = 8b): z1 rows p0..p0+7 (slots 0..7)
// and z2 rows p0..p0+7 (slots 8..15).  Wave w owns slots {w,4+w,8+w,12+w};
// it=0/it=2 are the SAME pair (p0+w), it=1/it=3 pair (p0+4+w).
// zT16[(c2*8192 + row)*16] : c2 = quad*4 + kk, entry = 16 bytes =
//   z[row][64kk+8q .. +7] ++ z[row][64kk+32+8q .. +7]
__global__ void __launch_bounds__(256) prep_kernel(
        const float* __restrict__ z1, const float* __restrict__ z2,
        unsigned char* __restrict__ zT16, float* __restrict__ pairpart) {
    __shared__ int Ls[16 * 64];   // 16 rows x 256B (fp8)
    __shared__ float wp[4];
    const int tid  = threadIdx.x;
    const int wave = tid >> 6;
    const int lane = tid & 63;
    const int p0   = blockIdx.x * 8;

    float4 v[4];
    float  invn[4];
    #pragma unroll
    for (int it = 0; it < 4; ++it) {
        const int s  = it * 4 + wave;          // slot 0..15
        const int pr = p0 + (s & 7);           // pair index
        const float* src = (s < 8) ? (z1 + (size_t)pr * DIM)
                                   : (z2 + (size_t)pr * DIM);
        v[it] = ((const float4*)src)[lane];
        float ss = sum64(v[it].x * v[it].x + v[it].y * v[it].y
                       + v[it].z * v[it].z + v[it].w * v[it].w);
        invn[it] = 1.0f / fmaxf(sqrtf(ss), 1e-12f);
        int p = __builtin_amdgcn_cvt_pk_fp8_f32(
                    v[it].x * invn[it], v[it].y * invn[it], 0, false);
        p     = __builtin_amdgcn_cvt_pk_fp8_f32(
                    v[it].z * invn[it], v[it].w * invn[it], p, true);
        Ls[s * 64 + lane] = p;
    }
    // pair sims: (it0,it2) = pair p0+wave, (it1,it3) = pair p0+4+wave
    {
        float d0 = sum64(v[0].x * v[2].x + v[0].y * v[2].y
                       + v[0].z * v[2].z + v[0].w * v[2].w);
        float d1 = sum64(v[1].x * v[3].x + v[1].y * v[3].y
                       + v[1].z * v[3].z + v[1].w * v[3].w);
        if (lane == 0)
            wp[wave] = (d0 * invn[0] * invn[2] + d1 * invn[1] * invn[3]) * 10.0f;
    }
    __syncthreads();
    // thread t -> c2 = t>>4, row-slot r = t&15
    const int c2 = tid >> 4;
    const int r  = tid & 15;
    const int grow = (r < 8) ? (p0 + r) : (NPAIR + p0 + (r - 8));
    const int quad = c2 >> 2;
    const int kk   = c2 & 3;
    const int d0i = 16 * kk + 2 * quad;
    int4 o;
    o.x = Ls[r * 64 + d0i];
    o.y = Ls[r * 64 + d0i + 1];
    o.z = Ls[r * 64 + d0i + 8];
    o.w = Ls[r * 64 + d0i + 9];
    *(int4*)(zT16 + ((size_t)c2 * ROWS + grow) * 16) = o;
    if (tid == 0)
        pairpart[blockIdx.x] = wp[0] + wp[1] + wp[2] + wp[3];
}

// ---------------- K2: symmetric fp8 Gram, LDS-staged ----------------
// LDS: A panel [0,32KB), B panel [32KB,64KB).
// Panel layout: 32 groups of 1KB, group g: kk = g>>3, ig = g&7.
// DMA dest is wave-uniform base + lane*16 -> internal order [q][row][16B];
// compute reads whole 1KB groups contiguously -> 0 bank conflicts.
__global__ void __launch_bounds__(256, 2) simsum_kernel(
        const unsigned char* __restrict__ zT16, float* __restrict__ partial) {
    // decode linear tile index -> (by, bx), bx >= by
    const int t = blockIdx.x;
    int by = (int)floorf((129.0f - sqrtf(16641.0f - 8.0f * (float)t)) * 0.5f);
    by = max(0, min(by, 63));
    while (64 * (by + 1) - ((by + 1) * by) / 2 <= t) by++;
    while (64 * by - (by * (by - 1)) / 2 > t) by--;
    const int bx = by + (t - (64 * by - (by * (by - 1)) / 2));
    const int rowBase = by * 128;
    const int colBase = bx * 128;

    const int tid  = threadIdx.x;
    const int wave = tid >> 6;
    const int lane = tid & 63;
    const int lc   = lane & 15;
    const int quad = lane >> 4;
    const int waveRow = (wave >> 1) * 64;
    const int waveCol = (wave & 1) * 64;

    __shared__ __align__(16) unsigned char lds[65536];

    // ---- stage both panels: waves 0,1 -> A rows, waves 2,3 -> B cols ----
    {
        const int halfSel = wave >> 1;                   // 0=A, 1=B
        const int pbase   = halfSel ? colBase : rowBase; // panel row base
        #pragma unroll
        for (int it = 0; it < 16; ++it) {
            const int g  = ((wave & 1) << 4) | it;       // 0..31
            const int kk = g >> 3;
            const int ig = g & 7;
            const unsigned char* src = zT16
                + ((size_t)(4 * quad + kk) * ROWS + pbase + 16 * ig + lc) * 16;
            __builtin_amdgcn_global_load_lds(
                (const __attribute__((address_space(1))) unsigned int*)src,
                (__attribute__((address_space(3))) unsigned int*)
                    &lds[(halfSel << 15) + kk * 8192 + ig * 1024],
                16, 0, 0);
        }
    }
    __syncthreads();

    // ---- compute: pure ds_read_b128 + MFMA ----
    const int aig = (wave >> 1) * 4;   // A group-row base for this wave
    const int bgi = (wave & 1) * 4;    // B group-row base for this wave
    const unsigned char* lA = &lds[quad * 256 + lc * 16];
    const unsigned char* lB = &lds[32768 + quad * 256 + lc * 16];

    f32x4 acc[4][4];
    #pragma unroll
    for (int i = 0; i < 4; i++)
        #pragma unroll
        for (int j = 0; j < 4; j++)
            acc[i][j] = (f32x4)(0.0f);

    #pragma unroll
    for (int kk = 0; kk < 4; kk++) {
        l2v va[4], vb[4];
        #pragma unroll
        for (int i = 0; i < 4; i++)
            va[i] = *(const l2v*)(lA + kk * 8192 + (aig + i) * 1024);
        #pragma unroll
        for (int j = 0; j < 4; j++)
            vb[j] = *(const l2v*)(lB + kk * 8192 + (bgi + j) * 1024);
        // ks = 2kk (lo halves)
        #pragma unroll
        for (int i = 0; i < 4; i++)
            #pragma unroll
            for (int j = 0; j < 4; j++)
                acc[i][j] = __builtin_amdgcn_mfma_f32_16x16x32_fp8_fp8(
                    va[i].x, vb[j].x, acc[i][j], 0, 0, 0);
        // ks = 2kk+1 (hi halves)
        #pragma unroll
        for (int i = 0; i < 4; i++)
            #pragma unroll
            for (int j = 0; j < 4; j++)
                acc[i][j] = __builtin_amdgcn_mfma_f32_16x16x32_fp8_fp8(
                    va[i].y, vb[j].y, acc[i][j], 0, 0, 0);
    }

    // Epilogue. C/D 16x16: col=lane&15, row=quad*4+reg [m89].
    // Privatized unique-writer slots, SLOT-MAJOR: partial[slot*8192 + row].
    float* prow = partial + (size_t)(bx * 2 + (waveCol >> 6)) * ROWS;
    if (bx == by) {
        #pragma unroll
        for (int i = 0; i < 4; i++) {
            #pragma unroll
            for (int r = 0; r < 4; r++) {
                const int grow = rowBase + waveRow + 16 * i + quad * 4 + r;
                float s = 0.0f;
                #pragma unroll
                for (int j = 0; j < 4; j++) {
                    const int gcol = colBase + waveCol + 16 * j + lc;
                    float e = __builtin_amdgcn_exp2f(acc[i][j][r] * EXP_SCALE);
                    s += (grow == gcol) ? 0.0f : e;
                }
                s = sum16(s);
                if (lc == 0) prow[grow] = s;
            }
        }
    } else {
        float* pcol = partial + (size_t)(by * 2 + (waveRow >> 6)) * ROWS;
        float colacc[4] = {0.0f, 0.0f, 0.0f, 0.0f};
        #pragma unroll
        for (int i = 0; i < 4; i++) {
            #pragma unroll
            for (int r = 0; r < 4; r++) {
                const int grow = rowBase + waveRow + 16 * i + quad * 4 + r;
                float s = 0.0f;
                #pragma unroll
                for (int j = 0; j < 4; j++) {
                    float e = __builtin_amdgcn_exp2f(acc[i][j][r] * EXP_SCALE);
                    s += e;
                    colacc[j] += e;
                }
                s = sum16(s);
                if (lc == 0) prow[grow] = s;
            }
        }
        #pragma unroll
        for (int j = 0; j < 4; j++) {
            float c = colacc[j];
            c += __shfl_xor(c, 16);
            c += __shfl_xor(c, 32);
            if (lane < 16) pcol[colBase + waveCol + 16 * j + lc] = c;
        }
    }
}

// ---------------- K3: partial -> sum of log(rowsum) per 64 rows ----------
__global__ void __launch_bounds__(256) logsum_kernel(
        const float* __restrict__ partial, float* __restrict__ logpart) {
    const int tid  = threadIdx.x;
    const int wave = tid >> 6;
    const int lane = tid & 63;
    const int r0 = blockIdx.x * 64;
    float s = 0.0f;
    #pragma unroll
    for (int k = 0; k < 32; ++k) {
        const int slot = wave + k * 4;
        s += partial[(size_t)slot * ROWS + r0 + lane];
    }
    __shared__ float red[4][64];
    red[wave][lane] = s;
    __syncthreads();
    if (wave == 0) {
        float rs = red[0][lane] + red[1][lane] + red[2][lane] + red[3][lane];
        float lg = logf(rs);
        lg = sum64(lg);
        if (lane == 0) logpart[blockIdx.x] = lg;
    }
}

// ---------------- K4: final reduce (single block) ----------------
// out = (sum_{128} logpart - 2 * sum_{512} pairpart) / 8192
__global__ void __launch_bounds__(256) final_kernel(
        const float* __restrict__ logpart, const float* __restrict__ pairpart,
        float* __restrict__ out) {
    const int tid = threadIdx.x;
    float s = -2.0f * (pairpart[tid] + pairpart[tid + 256]);
    if (tid < 128) s += logpart[tid];
    s = sum64(s);
    __shared__ float wpart[4];
    if ((tid & 63) == 0) wpart[tid >> 6] = s;
    __syncthreads();
    if (tid == 0)
        out[0] = (wpart[0] + wpart[1] + wpart[2] + wpart[3]) * (1.0f / ROWS);
}

extern "C" void kernel_launch(void* const* d_in, const int* in_sizes, int n_in,
                              void* d_out, int out_size, void* d_ws, size_t ws_size,
                              hipStream_t stream) {
    const float* z1 = (const float*)d_in[0];
    const float* z2 = (const float*)d_in[1];
    float* out = (float*)d_out;

    char* ws = (char*)d_ws;
    unsigned char* zT16 = (unsigned char*)ws;                       // 2 MiB
    float* partial  = (float*)(ws + (size_t)2 * 1024 * 1024);       // 4 MiB [slot][row]
    float* pairpart = (float*)(ws + (size_t)6 * 1024 * 1024);       // 2 KiB (512)
    float* logpart  = (float*)(ws + (size_t)6 * 1024 * 1024 + 4096);// 512 B (128)

    prep_kernel<<<NPAIR / 8, 256, 0, stream>>>(z1, z2, zT16, pairpart);
    simsum_kernel<<<NTILE, 256, 0, stream>>>(zT16, partial);
    logsum_kernel<<<ROWS / 64, 256, 0, stream>>>(partial, logpart);
    final_kernel<<<1, 256, 0, stream>>>(logpart, pairpart, out);
}